// Round 15
// baseline (58.722 us; speedup 1.0000x reference)
//
#include <hip/hip_runtime.h>
#include <hip/hip_bf16.h>

typedef __attribute__((ext_vector_type(8))) short short8;   // 8 x bf16 (4 VGPR)
typedef __attribute__((ext_vector_type(4))) float f32x4;
typedef __attribute__((ext_vector_type(4))) int   i32x4;

#define KD 4096
#define ND 16384
#define MD 128

// round-to-nearest-even f32 -> bf16 bits
__device__ __forceinline__ ushort f2bf_rn(float f) {
    unsigned u = __float_as_uint(f);
    u += 0x7FFFu + ((u >> 16) & 1u);
    return (ushort)(u >> 16);
}

// exact for |v| <= 127: int -> f32 -> truncate to bf16 (small ints have zero low mantissa bits)
__device__ __forceinline__ ushort i2bf(int v) {
    return (ushort)(__float_as_uint((float)v) >> 16);
}

// Pack x[128][4096] f32 into bf16 MFMA A-fragment order (verified r1/r3):
// xp[kb][mt][lane][j] = x[16*mt + (lane&15)][32*kb + 8*(lane>>4) + j]   (1 MiB)
__global__ __launch_bounds__(256) void pack_x_kernel(const float* __restrict__ x,
                                                     ushort* __restrict__ xp) {
    int tid  = blockIdx.x * 256 + threadIdx.x;   // 0..65535
    int lane = tid & 63;
    int mt   = (tid >> 6) & 7;
    int kb   = tid >> 9;                          // 0..127
    int m = (mt << 4) + (lane & 15);
    int k = (kb << 5) + ((lane >> 4) << 3);
    const f32x4* src = reinterpret_cast<const f32x4*>(x + (size_t)m * KD + k);
    f32x4 a = src[0];
    f32x4 b = src[1];
    short8 v;
    v[0] = (short)f2bf_rn(a[0]); v[1] = (short)f2bf_rn(a[1]);
    v[2] = (short)f2bf_rn(a[2]); v[3] = (short)f2bf_rn(a[3]);
    v[4] = (short)f2bf_rn(b[0]); v[5] = (short)f2bf_rn(b[1]);
    v[6] = (short)f2bf_rn(b[2]); v[7] = (short)f2bf_rn(b[3]);
    *reinterpret_cast<short8*>(xp + (size_t)tid * 8) = v;
}

#define GLOAD_LDS16(g, l)                                                        \
    __builtin_amdgcn_global_load_lds((const __attribute__((address_space(1))) void*)(g), \
                                     (__attribute__((address_space(3))) void*)(l), 16, 0, 0)

// Producer/consumer wave specialization — r10 verbatim except pipeline depth 3 -> 4.
// Block = 512 threads (8 waves), grid 256 (1 block/CU). Tile: 64 cols x 128 rows x full K.
//   waves 0..3  CONSUMERS: 16 cols each, acc[8]; plain __syncthreads() (vmcnt queue
//               empty -> implicit drain free; no gload_lds aliasing in consumer code).
//   waves 4..7  PRODUCERS: 8 gload_lds per stage (A first - L2-fast, then W - HBM),
//               issue 3 ahead, raw s_barrier + counted vmcnt(16): TWO full stages
//               (16 loads/wave = 64 KiB/CU) in flight at every wait point.
// LDS: A 4x16K [0,64K) + W 4x16K [64K,128K), stage s -> buffer s&3.
__global__ __launch_bounds__(512) void gemm_kernel(const int* __restrict__ wgt,
                                                   const ushort* __restrict__ xp,
                                                   const float* __restrict__ scales,
                                                   const float* __restrict__ bias,
                                                   float* __restrict__ out) {
    __shared__ __align__(16) char lds[131072];

    const int tid  = threadIdx.x;
    const int lane = tid & 63;
    const int w    = tid >> 6;          // wave 0..7
    const int n0   = blockIdx.x << 6;   // 256 blocks x 64 cols
    const int cl   = lane & 15;
    const int cq   = lane >> 4;         // 0..3

    if (w >= 4) {
        // ================= PRODUCER (r10 verbatim, depth-4) =================
        const int p = w - 4;            // 0..3
        // A: segments s = p*4+i, linear copy of xp chunk t
        const char* asrc = (const char*)xp + (p << 12) + (lane << 4);
        // W: cols c = 16p + 4i + cq, pre-swizzled source (verified layout:
        // off(c,k) = c*256 + ((4k) ^ ((c&7)<<4)))
        const int* wsrc0;
        const int* wsrc1;
        const int* wsrc2;
        const int* wsrc3;
        {
            int c0 = (p << 4) + 0  + cq;
            int c1 = (p << 4) + 4  + cq;
            int c2 = (p << 4) + 8  + cq;
            int c3 = (p << 4) + 12 + cq;
            wsrc0 = wgt + (size_t)(n0 + c0) * KD + ((cl ^ (c0 & 7)) << 2);
            wsrc1 = wgt + (size_t)(n0 + c1) * KD + ((cl ^ (c1 & 7)) << 2);
            wsrc2 = wgt + (size_t)(n0 + c2) * KD + ((cl ^ (c2 & 7)) << 2);
            wsrc3 = wgt + (size_t)(n0 + c3) * KD + ((cl ^ (c3 & 7)) << 2);
        }
        char* dA = lds + (p << 12);             // + b*16384 + i*1024
        char* dW = lds + 65536 + (p << 12);     // + b*16384 + i*1024

#define STAGE(t, b) do {                                                        \
            const char* _as = asrc + (size_t)(t) * 16384;                       \
            char* _dA = dA + (b) * 16384;                                       \
            GLOAD_LDS16(_as,        _dA);                                       \
            GLOAD_LDS16(_as + 1024, _dA + 1024);                                \
            GLOAD_LDS16(_as + 2048, _dA + 2048);                                \
            GLOAD_LDS16(_as + 3072, _dA + 3072);                                \
            const int _k0 = (t) * 64;                                           \
            char* _dW = dW + (b) * 16384;                                       \
            GLOAD_LDS16(wsrc0 + _k0, _dW);                                      \
            GLOAD_LDS16(wsrc1 + _k0, _dW + 1024);                               \
            GLOAD_LDS16(wsrc2 + _k0, _dW + 2048);                               \
            GLOAD_LDS16(wsrc3 + _k0, _dW + 3072);                               \
        } while (0)

        STAGE(0, 0);
        STAGE(1, 1);
        STAGE(2, 2);
        asm volatile("s_waitcnt vmcnt(16)" ::: "memory");   // stage 0 landed; 1,2 in flight
        __builtin_amdgcn_s_barrier();                        // entry barrier

#pragma unroll 1
        for (int t = 0; t < 64; ++t) {
            if (t + 3 < 64) {
                STAGE(t + 3, (t + 3) & 3);
                asm volatile("s_waitcnt vmcnt(16)" ::: "memory");  // stage t+1 landed
            } else if (t == 61) {
                asm volatile("s_waitcnt vmcnt(8)" ::: "memory");   // stage 62 landed
            } else if (t == 62) {
                asm volatile("s_waitcnt vmcnt(0)" ::: "memory");   // stage 63 landed
            }
            __builtin_amdgcn_s_barrier();
        }
#undef STAGE
        return;   // producers write no output
    }

    // ================= CONSUMER (waves 0..3, r10 verbatim) =================
    f32x4 acc[8];
#pragma unroll
    for (int i = 0; i < 8; ++i) acc[i] = (f32x4){0.f, 0.f, 0.f, 0.f};

    // read bases (verified r3/r10 patterns)
    const char* rA = lds + (lane << 4);                     // + b*16384 + j*8192 + mt*1024
    const char* rW = lds + 65536 + (((w << 4) + cl) << 8);  // + b*16384 + inner
    const unsigned sw  = (unsigned)((cl & 7) << 4);
    const unsigned q32 = (unsigned)(cq << 5);

    __syncthreads();                                        // entry barrier (vmcnt empty)

#pragma unroll 1
    for (int t = 0; t < 64; ++t) {
        const int bc = t & 3;
        const char* wb = rW + bc * 16384;
        const char* ab = rA + bc * 16384;
#pragma unroll
        for (int j = 0; j < 2; ++j) {
            unsigned off = (unsigned)((j << 7) + q32) ^ sw;
            i32x4 lo = *reinterpret_cast<const i32x4*>(wb + off);
            i32x4 hi = *reinterpret_cast<const i32x4*>(wb + (off ^ 16u));
            short8 bf;
            bf[0] = (short)i2bf(lo[0]); bf[1] = (short)i2bf(lo[1]);
            bf[2] = (short)i2bf(lo[2]); bf[3] = (short)i2bf(lo[3]);
            bf[4] = (short)i2bf(hi[0]); bf[5] = (short)i2bf(hi[1]);
            bf[6] = (short)i2bf(hi[2]); bf[7] = (short)i2bf(hi[3]);
            const char* aj = ab + j * 8192;
#pragma unroll
            for (int mt = 0; mt < 8; ++mt) {
                short8 af = *reinterpret_cast<const short8*>(aj + mt * 1024);
                acc[mt] = __builtin_amdgcn_mfma_f32_16x16x32_bf16(af, bf, acc[mt], 0, 0, 0);
            }
        }
        __syncthreads();
    }

    // ---- epilogue: scale + bias, direct store (block owns 128 x 64 tile) ----
    const int ncol = n0 + (w << 4) + cl;
    const float s  = scales[ncol] * (1.0f / 127.0f);
    const float bv = bias[ncol];
    const int rb = cq << 2;
#pragma unroll
    for (int mt = 0; mt < 8; ++mt) {
#pragma unroll
        for (int r = 0; r < 4; ++r) {
            int mg = (mt << 4) + rb + r;
            out[(size_t)mg * ND + ncol] = acc[mt][r] * s + bv;
        }
    }
}

extern "C" void kernel_launch(void* const* d_in, const int* in_sizes, int n_in,
                              void* d_out, int out_size, void* d_ws, size_t ws_size,
                              hipStream_t stream) {
    const float* x      = (const float*)d_in[0];
    const int*   wgt    = (const int*)d_in[1];     // int8 promoted to int32 by harness
    const float* scales = (const float*)d_in[2];
    const float* bias   = (const float*)d_in[3];
    float* out = (float*)d_out;
    ushort* xp = (ushort*)d_ws;                    // 1 MiB bf16 packed x

    pack_x_kernel<<<MD * KD / (8 * 256), 256, 0, stream>>>(x, xp);
    gemm_kernel<<<256, 512, 0, stream>>>(wgt, xp, scales, bias, out);
}

// Round 16
// 57.611 us; speedup vs baseline: 1.0193x; 1.0193x over previous
//
#include <hip/hip_runtime.h>
#include <hip/hip_bf16.h>

typedef __attribute__((ext_vector_type(8))) short short8;   // 8 x bf16 (4 VGPR)
typedef __attribute__((ext_vector_type(4))) float f32x4;
typedef __attribute__((ext_vector_type(4))) int   i32x4;

#define KD 4096
#define ND 16384
#define MD 128

// round-to-nearest-even f32 -> bf16 bits
__device__ __forceinline__ ushort f2bf_rn(float f) {
    unsigned u = __float_as_uint(f);
    u += 0x7FFFu + ((u >> 16) & 1u);
    return (ushort)(u >> 16);
}

// exact for |v| <= 127: int -> f32 -> truncate to bf16 (small ints have zero low mantissa bits)
__device__ __forceinline__ ushort i2bf(int v) {
    return (ushort)(__float_as_uint((float)v) >> 16);
}

// Pack x[128][4096] f32 into bf16 MFMA A-fragment order (verified r1/r3):
// xp[kb][mt][lane][j] = x[16*mt + (lane&15)][32*kb + 8*(lane>>4) + j]   (1 MiB)
__global__ __launch_bounds__(256) void pack_x_kernel(const float* __restrict__ x,
                                                     ushort* __restrict__ xp) {
    int tid  = blockIdx.x * 256 + threadIdx.x;   // 0..65535
    int lane = tid & 63;
    int mt   = (tid >> 6) & 7;
    int kb   = tid >> 9;                          // 0..127
    int m = (mt << 4) + (lane & 15);
    int k = (kb << 5) + ((lane >> 4) << 3);
    const f32x4* src = reinterpret_cast<const f32x4*>(x + (size_t)m * KD + k);
    f32x4 a = src[0];
    f32x4 b = src[1];
    short8 v;
    v[0] = (short)f2bf_rn(a[0]); v[1] = (short)f2bf_rn(a[1]);
    v[2] = (short)f2bf_rn(a[2]); v[3] = (short)f2bf_rn(a[3]);
    v[4] = (short)f2bf_rn(b[0]); v[5] = (short)f2bf_rn(b[1]);
    v[6] = (short)f2bf_rn(b[2]); v[7] = (short)f2bf_rn(b[3]);
    *reinterpret_cast<short8*>(xp + (size_t)tid * 8) = v;
}

#define GLOAD_LDS16(g, l)                                                        \
    __builtin_amdgcn_global_load_lds((const __attribute__((address_space(1))) void*)(g), \
                                     (__attribute__((address_space(3))) void*)(l), 16, 0, 0)

// Producer/consumer wave specialization — r10 verbatim except K-chunk STAGGER:
// block b starts its K loop at chunk (b & 63), wrapping mod 64. At any instant
// different blocks read different 256B k-windows of W -> HBM channel load spreads
// (lockstep phases + power-of-2 strides otherwise concentrate the whole GPU's
// demand into one channel-interleave window per phase).
// Block = 512 threads (8 waves), grid 256 (1 block/CU). Tile: 64 cols x 128 rows x full K.
//   waves 0..3  CONSUMERS: 16 cols each, acc[8]; plain __syncthreads() (vmcnt empty).
//   waves 4..7  PRODUCERS: 8 gload_lds per stage (4 A + 4 W), depth-3, issue 2 ahead,
//               raw s_barrier + counted vmcnt(8) (no ds_reads in producer waves).
// LDS: A 3x16K [0,48K) + W 3x16K [48K,96K), stage s -> buffer s%3.
__global__ __launch_bounds__(512) void gemm_kernel(const int* __restrict__ wgt,
                                                   const ushort* __restrict__ xp,
                                                   const float* __restrict__ scales,
                                                   const float* __restrict__ bias,
                                                   float* __restrict__ out) {
    __shared__ __align__(16) char lds[98304];

    const int tid  = threadIdx.x;
    const int lane = tid & 63;
    const int w    = tid >> 6;          // wave 0..7
    const int n0   = blockIdx.x << 6;   // 256 blocks x 64 cols
    const int boff = blockIdx.x & 63;   // per-block K-chunk stagger
    const int cl   = lane & 15;
    const int cq   = lane >> 4;         // 0..3

    if (w >= 4) {
        // ================= PRODUCER (r10 verbatim + stagger) =================
        const int p = w - 4;            // 0..3
        const char* asrc = (const char*)xp + (p << 12) + (lane << 4);
        const int* wsrc0;
        const int* wsrc1;
        const int* wsrc2;
        const int* wsrc3;
        {
            int c0 = (p << 4) + 0  + cq;
            int c1 = (p << 4) + 4  + cq;
            int c2 = (p << 4) + 8  + cq;
            int c3 = (p << 4) + 12 + cq;
            wsrc0 = wgt + (size_t)(n0 + c0) * KD + ((cl ^ (c0 & 7)) << 2);
            wsrc1 = wgt + (size_t)(n0 + c1) * KD + ((cl ^ (c1 & 7)) << 2);
            wsrc2 = wgt + (size_t)(n0 + c2) * KD + ((cl ^ (c2 & 7)) << 2);
            wsrc3 = wgt + (size_t)(n0 + c3) * KD + ((cl ^ (c3 & 7)) << 2);
        }
        char* dA = lds + (p << 12);             // + b*16384 + i*1024
        char* dW = lds + 49152 + (p << 12);     // + b*16384 + i*1024

        // kb = absolute K-chunk index (staggered); b = LDS buffer
#define STAGE(kb, b) do {                                                       \
            const char* _as = asrc + (size_t)(kb) * 16384;                      \
            char* _dA = dA + (b) * 16384;                                       \
            GLOAD_LDS16(_as,        _dA);                                       \
            GLOAD_LDS16(_as + 1024, _dA + 1024);                                \
            GLOAD_LDS16(_as + 2048, _dA + 2048);                                \
            GLOAD_LDS16(_as + 3072, _dA + 3072);                                \
            const int _k0 = (kb) * 64;                                          \
            char* _dW = dW + (b) * 16384;                                       \
            GLOAD_LDS16(wsrc0 + _k0, _dW);                                      \
            GLOAD_LDS16(wsrc1 + _k0, _dW + 1024);                               \
            GLOAD_LDS16(wsrc2 + _k0, _dW + 2048);                               \
            GLOAD_LDS16(wsrc3 + _k0, _dW + 3072);                               \
        } while (0)

        STAGE(boff, 0);
        STAGE((boff + 1) & 63, 1);
        asm volatile("s_waitcnt vmcnt(8)" ::: "memory");   // stage 0 landed
        __builtin_amdgcn_s_barrier();                       // entry barrier

        int b2 = 2;                      // buffer of logical stage t+2
#pragma unroll 1
        for (int t = 0; t < 64; ++t) {
            if (t + 2 < 64) {
                STAGE((t + 2 + boff) & 63, b2);
                asm volatile("s_waitcnt vmcnt(8)" ::: "memory");  // stage t+1 landed
            } else if (t + 1 < 64) {
                asm volatile("s_waitcnt vmcnt(0)" ::: "memory");  // stage 63 landed
            }
            __builtin_amdgcn_s_barrier();
            b2 = (b2 == 2) ? 0 : b2 + 1;
        }
#undef STAGE
        return;   // producers write no output
    }

    // ================= CONSUMER (waves 0..3, r10 verbatim) =================
    f32x4 acc[8];
#pragma unroll
    for (int i = 0; i < 8; ++i) acc[i] = (f32x4){0.f, 0.f, 0.f, 0.f};

    // read bases (verified r3/r10 patterns)
    const char* rA = lds + (lane << 4);                     // + b*16384 + j*8192 + mt*1024
    const char* rW = lds + 49152 + (((w << 4) + cl) << 8);  // + b*16384 + inner
    const unsigned sw  = (unsigned)((cl & 7) << 4);
    const unsigned q32 = (unsigned)(cq << 5);

    __syncthreads();                                        // entry barrier (vmcnt empty)

    int bc = 0;
#pragma unroll 1
    for (int t = 0; t < 64; ++t) {
        const char* wb = rW + bc * 16384;
        const char* ab = rA + bc * 16384;
#pragma unroll
        for (int j = 0; j < 2; ++j) {
            unsigned off = (unsigned)((j << 7) + q32) ^ sw;
            i32x4 lo = *reinterpret_cast<const i32x4*>(wb + off);
            i32x4 hi = *reinterpret_cast<const i32x4*>(wb + (off ^ 16u));
            short8 bf;
            bf[0] = (short)i2bf(lo[0]); bf[1] = (short)i2bf(lo[1]);
            bf[2] = (short)i2bf(lo[2]); bf[3] = (short)i2bf(lo[3]);
            bf[4] = (short)i2bf(hi[0]); bf[5] = (short)i2bf(hi[1]);
            bf[6] = (short)i2bf(hi[2]); bf[7] = (short)i2bf(hi[3]);
            const char* aj = ab + j * 8192;
#pragma unroll
            for (int mt = 0; mt < 8; ++mt) {
                short8 af = *reinterpret_cast<const short8*>(aj + mt * 1024);
                acc[mt] = __builtin_amdgcn_mfma_f32_16x16x32_bf16(af, bf, acc[mt], 0, 0, 0);
            }
        }
        __syncthreads();
        bc = (bc == 2) ? 0 : bc + 1;
    }

    // ---- epilogue: scale + bias, direct store (block owns 128 x 64 tile) ----
    const int ncol = n0 + (w << 4) + cl;
    const float s  = scales[ncol] * (1.0f / 127.0f);
    const float bv = bias[ncol];
    const int rb = cq << 2;
#pragma unroll
    for (int mt = 0; mt < 8; ++mt) {
#pragma unroll
        for (int r = 0; r < 4; ++r) {
            int mg = (mt << 4) + rb + r;
            out[(size_t)mg * ND + ncol] = acc[mt][r] * s + bv;
        }
    }
}

extern "C" void kernel_launch(void* const* d_in, const int* in_sizes, int n_in,
                              void* d_out, int out_size, void* d_ws, size_t ws_size,
                              hipStream_t stream) {
    const float* x      = (const float*)d_in[0];
    const int*   wgt    = (const int*)d_in[1];     // int8 promoted to int32 by harness
    const float* scales = (const float*)d_in[2];
    const float* bias   = (const float*)d_in[3];
    float* out = (float*)d_out;
    ushort* xp = (ushort*)d_ws;                    // 1 MiB bf16 packed x

    pack_x_kernel<<<MD * KD / (8 * 256), 256, 0, stream>>>(x, xp);
    gemm_kernel<<<256, 512, 0, stream>>>(wgt, xp, scales, bias, out);
}